// Round 6
// baseline (260.484 us; speedup 1.0000x reference)
//
#include <hip/hip_runtime.h>

#define NN 4096

// ---------------- Phase 1: fully-linear role-split partial sums -------------
// 1536 blocks. by<512: W role — block reads rows [8b, 8b+8) of w as ONE
// contiguous 32 KiB stream. by>=512: AH role — rows [4b, 4b+4) of alpha and
// hebb, two contiguous 16 KiB streams. Thread t owns 4 rotating column-quads
// (acc[q] covers float4 column 256*q + t), so partial rows keep natural
// column order and the reducer is unchanged.
__global__ __launch_bounds__(256, 4) void matvec_partial_kernel(
    const float* __restrict__ yin,
    const float* __restrict__ w,
    const float* __restrict__ alpha,
    const float* __restrict__ hebb,
    float* __restrict__ part1,   // 512 rows  (W partials)
    float* __restrict__ part2)   // 1024 rows (AH partials)
{
    const int t  = threadIdx.x;
    const int by = blockIdx.x;

    float4 a0 = make_float4(0.f, 0.f, 0.f, 0.f);
    float4 a1 = a0, a2 = a0, a3 = a0;

    if (by < 512) {
        const int b = by;
        const float4* wb = reinterpret_cast<const float4*>(w) + (size_t)b * 8192;
        #pragma unroll
        for (int s = 0; s < 8; ++s) {
            const float4* wr = wb + s * 1024;
            const float4 L0 = wr[t];
            const float4 L1 = wr[256 + t];
            const float4 L2 = wr[512 + t];
            const float4 L3 = wr[768 + t];
            const float yv = yin[8 * b + s];
            a0.x += yv * L0.x; a0.y += yv * L0.y; a0.z += yv * L0.z; a0.w += yv * L0.w;
            a1.x += yv * L1.x; a1.y += yv * L1.y; a1.z += yv * L1.z; a1.w += yv * L1.w;
            a2.x += yv * L2.x; a2.y += yv * L2.y; a2.z += yv * L2.z; a2.w += yv * L2.w;
            a3.x += yv * L3.x; a3.y += yv * L3.y; a3.z += yv * L3.z; a3.w += yv * L3.w;
        }
        float4* pr = reinterpret_cast<float4*>(part1) + (size_t)b * 1024;
        pr[t] = a0; pr[256 + t] = a1; pr[512 + t] = a2; pr[768 + t] = a3;
    } else {
        const int b = by - 512;
        const float4* ab = reinterpret_cast<const float4*>(alpha) + (size_t)b * 4096;
        const float4* hb = reinterpret_cast<const float4*>(hebb)  + (size_t)b * 4096;
        #pragma unroll
        for (int s = 0; s < 4; ++s) {
            const float4* ar = ab + s * 1024;
            const float4* hr = hb + s * 1024;
            const float4 A0 = ar[t],       H0 = hr[t];
            const float4 A1 = ar[256 + t], H1 = hr[256 + t];
            const float4 A2 = ar[512 + t], H2 = hr[512 + t];
            const float4 A3 = ar[768 + t], H3 = hr[768 + t];
            const float yv = yin[4 * b + s];
            a0.x += yv * (A0.x * H0.x); a0.y += yv * (A0.y * H0.y);
            a0.z += yv * (A0.z * H0.z); a0.w += yv * (A0.w * H0.w);
            a1.x += yv * (A1.x * H1.x); a1.y += yv * (A1.y * H1.y);
            a1.z += yv * (A1.z * H1.z); a1.w += yv * (A1.w * H1.w);
            a2.x += yv * (A2.x * H2.x); a2.y += yv * (A2.y * H2.y);
            a2.z += yv * (A2.z * H2.z); a2.w += yv * (A2.w * H2.w);
            a3.x += yv * (A3.x * H3.x); a3.y += yv * (A3.y * H3.y);
            a3.z += yv * (A3.z * H3.z); a3.w += yv * (A3.w * H3.w);
        }
        float4* pr = reinterpret_cast<float4*>(part2) + (size_t)b * 1024;
        pr[t] = a0; pr[256 + t] = a1; pr[512 + t] = a2; pr[768 + t] = a3;
    }
}

// ---------------- Phase 2: reduce partials -> yout = tanh(sum + input) ------
// Grid 64 x 256. Block handles 64 columns; 4 row-slices, LDS-reduced.
__global__ __launch_bounds__(256) void reduce_yout_kernel(
    const float* __restrict__ part1,
    const float* __restrict__ part2,
    const float* __restrict__ input,
    float* __restrict__ yout)
{
    const int tid   = threadIdx.x;
    const int j     = blockIdx.x * 64 + (tid & 63);
    const int slice = tid >> 6;           // 0..3

    float s = 0.f;
    #pragma unroll 8
    for (int kk = 0; kk < 128; ++kk)
        s += part1[(size_t)(slice * 128 + kk) * NN + j];
    #pragma unroll 8
    for (int kk = 0; kk < 256; ++kk)
        s += part2[(size_t)(slice * 256 + kk) * NN + j];

    __shared__ float sm[256];
    sm[tid] = s;
    __syncthreads();
    if (tid < 64) {
        float tot = sm[tid] + sm[tid + 64] + sm[tid + 128] + sm[tid + 192];
        yout[j] = tanhf(tot + input[j]);
    }
}

// ---------------- Phase 3: hebb' = (1-eta)*hebb + eta*outer(yin,yout) -------
// 2048 blocks x 256 threads x 8 float4 = exactly NN*NN floats; per-iteration
// the grid sweeps a contiguous 8 MiB window. Overwrites the part2 scratch.
__global__ __launch_bounds__(256, 8) void hebb_update_kernel(
    const float* __restrict__ hebb,
    const float* __restrict__ yin,
    const float* __restrict__ yout,
    const float* __restrict__ eta_p,
    float* __restrict__ hebb_out)
{
    const float eta = eta_p[0];
    const float om  = 1.0f - eta;
    const int tid   = blockIdx.x * 256 + threadIdx.x;   // 0..524287
    const int NT    = 2048 * 256;                       // stride in float4

    const float4 yo = reinterpret_cast<const float4*>(yout)[tid & 1023];

    #pragma unroll
    for (int half = 0; half < 2; ++half) {
        float4 hv[4];
        float  ye[4];
        #pragma unroll
        for (int it = 0; it < 4; ++it) {
            const int g = tid + (half * 4 + it) * NT;
            hv[it] = reinterpret_cast<const float4*>(hebb)[g];
            ye[it] = eta * yin[g >> 10];
        }
        #pragma unroll
        for (int it = 0; it < 4; ++it) {
            const int g = tid + (half * 4 + it) * NT;
            float4 r;
            r.x = om * hv[it].x + ye[it] * yo.x;
            r.y = om * hv[it].y + ye[it] * yo.y;
            r.z = om * hv[it].z + ye[it] * yo.z;
            r.w = om * hv[it].w + ye[it] * yo.w;
            reinterpret_cast<float4*>(hebb_out)[g] = r;
        }
    }
}

extern "C" void kernel_launch(void* const* d_in, const int* in_sizes, int n_in,
                              void* d_out, int out_size, void* d_ws, size_t ws_size,
                              hipStream_t stream) {
    const float* input = (const float*)d_in[0];
    const float* yin   = (const float*)d_in[1];
    const float* hebb  = (const float*)d_in[2];
    const float* w     = (const float*)d_in[3];
    const float* alpha = (const float*)d_in[4];
    const float* eta   = (const float*)d_in[5];

    float* out      = (float*)d_out;
    float* yout     = out;        // first NN elements
    float* hebb_out = out + NN;   // next NN*NN elements (written last by K3)

    float* part1 = (float*)d_ws;  // 512 rows = 8 MiB
    float* part2 = hebb_out;      // 1024 rows = 16 MiB scratch inside d_out,
                                  // fully overwritten by hebb_update afterwards

    matvec_partial_kernel<<<1536, 256, 0, stream>>>(yin, w, alpha, hebb,
                                                    part1, part2);

    reduce_yout_kernel<<<NN / 64, 256, 0, stream>>>(part1, part2, input, yout);

    hebb_update_kernel<<<2048, 256, 0, stream>>>(hebb, yin, yout, eta, hebb_out);
}